// Round 6
// baseline (648.720 us; speedup 1.0000x reference)
//
#include <hip/hip_runtime.h>
#include <hip/hip_bf16.h>
#include <stdint.h>

// SelfAttention: out = softmax((x Wq^T)(x Wk^T)^T / sqrt(D)) (x Wv^T)
// SEQ=8192, D=1024, fp32 in/out. All GEMMs bf16 MFMA.
// R15 = R14 with the template-dependent LDS bug fixed (R14 never ran: the
// BDIR=0 instantiation indexed a 1-D conditional Bs array as 2-D -> compile
// error at PV instantiation). Theory unchanged:
//   R9-R13 (schedules: 2ph/coarse/8ph/min-sync, tiles 128/256) all 203-215us
//   @ 24-29% MfmaUtil -> schedule-invariant. Budget: LDS port (reads 192KB +
//   DMA 64KB ~= 3.8k cyc @85B/cyc) + MFMA 2.5k ~= measured 6.3k cyc/K-tile
//   => LDS-pipe serialized against MFMA. Fix: stream B frags L2->VGPR
//   (lanes {lr,lr+16,lr+32,lr+48} read one contiguous 64B line = full-line
//   coalescing, same data the LDS path delivered). B double-buffered in regs
//   (64 VGPR), loaded one K-tile ahead; A keeps LDS (4x reuse, 64KB dbuf).
//   LDS-port traffic/K-tile: 256KB -> 160KB; B bytes move to the VMEM pipe.
// BDIR=1: QKV + S-GEMM (B panels L2-hot). BDIR=0: PV keeps all-LDS R13 path.
// Keeps: row-rotation LDS swizzle (0 conflicts), GROUP_M=8 grouping, compact
// q/k/v de-interleave, fused softmax epilogues, split-K=2 PV.
//
// Workspace (~230 MB): x_bf16 16 | Wcat 6 | q 16 | k 16 | v 16 | S 128 | pv 32
//                      | lsum 32KB

#define SEQ 8192
#define DMODEL 1024
#define LOG2E 1.44269504088896340736f
#define GROUP_M 8

typedef __bf16 bf16_t;
typedef __bf16 bf16x8 __attribute__((ext_vector_type(8)));
typedef float f32x4 __attribute__((ext_vector_type(4)));

// ---------------- fp32 -> bf16 convert ----------------
__global__ __launch_bounds__(256)
void convert_f32_bf16(const float* __restrict__ in, bf16_t* __restrict__ out, long n) {
    long i = ((long)blockIdx.x * 256 + threadIdx.x) * 4;
    if (i + 3 < n) {
        const float4 v = *(const float4*)(in + i);
        union { ushort4 u; bf16_t b[4]; } p;
        p.b[0] = (bf16_t)v.x; p.b[1] = (bf16_t)v.y;
        p.b[2] = (bf16_t)v.z; p.b[3] = (bf16_t)v.w;
        *(ushort4*)(out + i) = p.u;
    }
}

// ---------------- fp32 add: out += part ----------------
__global__ __launch_bounds__(256)
void add_f32(float* __restrict__ out, const float* __restrict__ part, long n) {
    long i = ((long)blockIdx.x * 256 + threadIdx.x) * 4;
    if (i + 3 < n) {
        float4 a = *(const float4*)(out + i);
        const float4 b = *(const float4*)(part + i);
        a.x += b.x; a.y += b.y; a.z += b.z; a.w += b.w;
        *(float4*)(out + i) = a;
    }
}

// ---------------- zero fp32 buffer ----------------
__global__ __launch_bounds__(256)
void zero_f32(float* __restrict__ p, int n) {
    int i = blockIdx.x * 256 + threadIdx.x;
    if (i < n) p[i] = 0.0f;
}

// ---------------- NT GEMM: C[M,N] = A[M,K] @ B[N,K]^T ----------------
// 256x256 tile, BK=64, 512 threads (8 waves as 2x4), per-wave 128x64 via
// 8x4 grid of mfma_f32_16x16x32_bf16.
// BDIR=1: A via LDS (double-buffered, 64KB), B direct global->reg frags
//         (double-buffered, loaded one K-tile ahead). One barrier + one
//         vmcnt(0) per K-tile (tile-t loads issued a full tile prior).
// BDIR=0: both operands via LDS (R13 structure) - used by PV.
// MODE 0: C = alpha*acc. MODE 1: C = exp2(alpha*acc) bf16 + atomic row sums.
// MODE 2: C = acc / lsum[row].
template <typename OutT, int MODE, int BDIR>
__global__ __launch_bounds__(512, 2)
void gemm_nt(const bf16_t* __restrict__ A, const bf16_t* __restrict__ B,
             OutT* __restrict__ C0, OutT* __restrict__ C1,
             float* __restrict__ lsum,
             int M, int N, int Kps, int lda, int ldb, int ldc,
             long plane, int cshift, float alpha)
{
    // LDS: A dbuf at [0),[16384); B dbuf (BDIR=0 only) at [32768),[49152).
    __shared__ bf16_t smem[(BDIR ? 2 : 4) * 16384];

    const int tid  = threadIdx.x;
    const int wave = tid >> 6;
    const int lane = tid & 63;

    const int nbm = M >> 8, nbn = N >> 8;
    const int tiles = nbm * nbn;
    int bid = blockIdx.x;
    const int sid = bid / tiles;        // split-K id
    bid -= sid * tiles;
    const long kbase = (long)sid * Kps;
    OutT* __restrict__ C = sid ? C1 : C0;

    // grouped swizzle for L2 locality
    const int per_group = GROUP_M * nbn;
    const int gid   = bid / per_group;
    const int rem   = bid - gid * per_group;
    const int first = gid * GROUP_M;
    const int gsz   = min(nbm - first, GROUP_M);
    const int bm    = first + rem % gsz;
    const int bn    = rem / gsz;
    const long row0 = (long)bm * 256;
    const long col0 = (long)bn * 256;

    const int wm = (wave >> 2) * 128;  // wave's 128x64 sub-tile
    const int wn = (wave & 3) * 64;
    const int lr = lane & 15;          // fragment non-K index
    const int lq = lane >> 4;          // quad 0..3 -> k-chunk / row group

    // --- staging addresses: rows rt=tid>>3 per 64-row block i; phys slot
    // p=tid&7 holds global chunk (p+r)&7 (rotation within the 128B row).
    const int rt = tid >> 3;
    const int sl = ((tid & 7) + rt) & 7;
    const bf16_t* pa = A + (row0 + rt) * (long)lda + kbase + sl * 8;
    const bf16_t* pb = B + (col0 + rt) * (long)ldb + kbase + sl * 8;

    // --- LDS read offsets (rotation): p = (chunk - row)&7, row&7 == lr&7.
    const int p0  = (lq - lr) & 7;          // ks=0 chunk = lq
    const int p1  = p0 ^ 4;                 // ks=1 chunk = 4+lq
    const int oA0 = (wm + lr) * 64 + p0 * 8;
    const int oA1 = (wm + lr) * 64 + p1 * 8;
    const int oB0 = (wn + lr) * 64 + p0 * 8;
    const int oB1 = (wn + lr) * 64 + p1 * 8;

    const int nt = Kps >> 6;

    f32x4 acc[8][4] = {};

    // Stage one 256x64 operand tile (4 row-blocks) into LDS at base.
#define STG4(kt, base, psrc, ld)                                                \
    {                                                                           \
        _Pragma("unroll")                                                       \
        for (int i = 0; i < 4; ++i) {                                           \
            const bf16_t* g_ = (psrc) + (long)(kt) * 64 + (long)i * 64 * (ld);  \
            __builtin_amdgcn_global_load_lds(                                   \
                (const __attribute__((address_space(1))) uint32_t*)g_,          \
                (__attribute__((address_space(3))) uint32_t*)((base) + i * 4096 + tid * 8), \
                16, 0, 0);                                                      \
        }                                                                       \
    }

    if constexpr (BDIR) {
        // ---- B fragment pointers: per-lane, one base per ni sub-tile.
        // Lane (lq,lr) reads B[col0+wn+ni*16+lr][lq*8 + ks*32 ..+8): lanes
        // {lr,lr+16,lr+32,lr+48} form one contiguous 64B line.
        const bf16_t* gB[4];
        #pragma unroll
        for (int ni = 0; ni < 4; ++ni)
            gB[ni] = B + (col0 + wn + ni * 16 + lr) * (long)ldb + kbase + lq * 8;

        bf16x8 bA[8], bB[8];   // [ni*2+ks], double-buffered across K-tiles

        // Prologue: B(0) -> bA, A(0) -> LDS buf0.
        #pragma unroll
        for (int ni = 0; ni < 4; ++ni) {
            bA[ni * 2 + 0] = *(const bf16x8*)(gB[ni]);
            bA[ni * 2 + 1] = *(const bf16x8*)(gB[ni] + 32);
        }
        STG4(0, smem, pa, lda);
        #pragma unroll
        for (int ni = 0; ni < 4; ++ni) gB[ni] += 64;

#define BDIR_BODY(t, BU, BF)                                                    \
        {                                                                       \
            const int c_ = (t) & 1;                                             \
            const bf16_t* as = smem + c_ * 16384;                               \
            /* tile t's A-DMA + B-regs (issued 1 tile ago) landed */            \
            asm volatile("s_waitcnt vmcnt(0)" ::: "memory");                    \
            __builtin_amdgcn_s_barrier();                                       \
            asm volatile("" ::: "memory");                                      \
            if ((t) + 1 < nt) {                                                 \
                _Pragma("unroll")                                               \
                for (int ni = 0; ni < 4; ++ni) {                                \
                    BF[ni * 2 + 0] = *(const bf16x8*)(gB[ni]);                  \
                    BF[ni * 2 + 1] = *(const bf16x8*)(gB[ni] + 32);             \
                }                                                               \
                STG4((t) + 1, smem + (c_ ^ 1) * 16384, pa, lda);                \
            }                                                                   \
            _Pragma("unroll")                                                   \
            for (int ni = 0; ni < 4; ++ni) gB[ni] += 64;                        \
            bf16x8 a0[4], a1[4];                                                \
            _Pragma("unroll")                                                   \
            for (int mi = 0; mi < 4; ++mi) {                                    \
                a0[mi] = *(const bf16x8*)(as + oA0 + mi * 1024);                \
                a1[mi] = *(const bf16x8*)(as + oA1 + mi * 1024);                \
            }                                                                   \
            __builtin_amdgcn_s_setprio(1);                                      \
            _Pragma("unroll")                                                   \
            for (int mi = 0; mi < 4; ++mi)                                      \
                _Pragma("unroll")                                               \
                for (int ni = 0; ni < 4; ++ni)                                  \
                    acc[mi][ni] = __builtin_amdgcn_mfma_f32_16x16x32_bf16(      \
                        a0[mi], BU[ni * 2 + 0], acc[mi][ni], 0, 0, 0);          \
            _Pragma("unroll")                                                   \
            for (int mi = 0; mi < 4; ++mi)                                      \
                _Pragma("unroll")                                               \
                for (int ni = 0; ni < 4; ++ni)                                  \
                    acc[mi][ni] = __builtin_amdgcn_mfma_f32_16x16x32_bf16(      \
                        a1[mi], BU[ni * 2 + 1], acc[mi][ni], 0, 0, 0);          \
            __builtin_amdgcn_s_setprio(0);                                      \
            bf16x8 a2[4], a3[4];                                                \
            _Pragma("unroll")                                                   \
            for (int mi = 0; mi < 4; ++mi) {                                    \
                a2[mi] = *(const bf16x8*)(as + oA0 + (mi + 4) * 1024);          \
                a3[mi] = *(const bf16x8*)(as + oA1 + (mi + 4) * 1024);          \
            }                                                                   \
            __builtin_amdgcn_s_setprio(1);                                      \
            _Pragma("unroll")                                                   \
            for (int mi = 0; mi < 4; ++mi)                                      \
                _Pragma("unroll")                                               \
                for (int ni = 0; ni < 4; ++ni)                                  \
                    acc[mi + 4][ni] = __builtin_amdgcn_mfma_f32_16x16x32_bf16(  \
                        a2[mi], BU[ni * 2 + 0], acc[mi + 4][ni], 0, 0, 0);      \
            _Pragma("unroll")                                                   \
            for (int mi = 0; mi < 4; ++mi)                                      \
                _Pragma("unroll")                                               \
                for (int ni = 0; ni < 4; ++ni)                                  \
                    acc[mi + 4][ni] = __builtin_amdgcn_mfma_f32_16x16x32_bf16(  \
                        a3[mi], BU[ni * 2 + 1], acc[mi + 4][ni], 0, 0, 0);      \
            __builtin_amdgcn_s_setprio(0);                                      \
        }

        for (int t = 0; t < nt; t += 2) {     // nt is even (16 or 64)
            BDIR_BODY(t,     bA, bB);
            BDIR_BODY(t + 1, bB, bA);
        }
#undef BDIR_BODY
    } else {
        // ---- R13 path: both operands via LDS (used by PV).
        bf16_t* const Bbase = smem + 2 * 16384;
        STG4(0, smem, pa, lda);
        STG4(0, Bbase, pb, ldb);

        for (int t = 0; t < nt; ++t) {
            const int c = t & 1;
            const bf16_t* as = smem  + c * 16384;
            const bf16_t* bs = Bbase + c * 16384;

            asm volatile("s_waitcnt vmcnt(0)" ::: "memory");
            __builtin_amdgcn_s_barrier();
            asm volatile("" ::: "memory");

            if (t + 1 < nt) {
                STG4(t + 1, smem  + (c ^ 1) * 16384, pa, lda);
                STG4(t + 1, Bbase + (c ^ 1) * 16384, pb, ldb);
            }

            bf16x8 a0k0[4], a0k1[4], b0k0[2], b0k1[2], b1k0[2], b1k1[2];
            #pragma unroll
            for (int mi = 0; mi < 4; ++mi) {
                a0k0[mi] = *(const bf16x8*)(as + oA0 + mi * 1024);
                a0k1[mi] = *(const bf16x8*)(as + oA1 + mi * 1024);
            }
            #pragma unroll
            for (int ni = 0; ni < 2; ++ni) {
                b0k0[ni] = *(const bf16x8*)(bs + oB0 + ni * 1024);
                b0k1[ni] = *(const bf16x8*)(bs + oB1 + ni * 1024);
                b1k0[ni] = *(const bf16x8*)(bs + oB0 + (ni + 2) * 1024);
                b1k1[ni] = *(const bf16x8*)(bs + oB1 + (ni + 2) * 1024);
            }

            __builtin_amdgcn_s_setprio(1);
            #pragma unroll
            for (int mi = 0; mi < 4; ++mi)
                #pragma unroll
                for (int ni = 0; ni < 2; ++ni)
                    acc[mi][ni] = __builtin_amdgcn_mfma_f32_16x16x32_bf16(
                        a0k0[mi], b0k0[ni], acc[mi][ni], 0, 0, 0);
            #pragma unroll
            for (int mi = 0; mi < 4; ++mi)
                #pragma unroll
                for (int ni = 0; ni < 2; ++ni)
                    acc[mi][ni] = __builtin_amdgcn_mfma_f32_16x16x32_bf16(
                        a0k1[mi], b0k1[ni], acc[mi][ni], 0, 0, 0);
            #pragma unroll
            for (int mi = 0; mi < 4; ++mi)
                #pragma unroll
                for (int ni = 0; ni < 2; ++ni)
                    acc[mi][ni + 2] = __builtin_amdgcn_mfma_f32_16x16x32_bf16(
                        a0k0[mi], b1k0[ni], acc[mi][ni + 2], 0, 0, 0);
            #pragma unroll
            for (int mi = 0; mi < 4; ++mi)
                #pragma unroll
                for (int ni = 0; ni < 2; ++ni)
                    acc[mi][ni + 2] = __builtin_amdgcn_mfma_f32_16x16x32_bf16(
                        a0k1[mi], b1k1[ni], acc[mi][ni + 2], 0, 0, 0);
            __builtin_amdgcn_s_setprio(0);

            bf16x8 a1k0[4], a1k1[4];
            #pragma unroll
            for (int mi = 0; mi < 4; ++mi) {
                a1k0[mi] = *(const bf16x8*)(as + oA0 + (mi + 4) * 1024);
                a1k1[mi] = *(const bf16x8*)(as + oA1 + (mi + 4) * 1024);
            }

            __builtin_amdgcn_s_setprio(1);
            #pragma unroll
            for (int mi = 0; mi < 4; ++mi)
                #pragma unroll
                for (int ni = 0; ni < 2; ++ni)
                    acc[mi + 4][ni] = __builtin_amdgcn_mfma_f32_16x16x32_bf16(
                        a1k0[mi], b0k0[ni], acc[mi + 4][ni], 0, 0, 0);
            #pragma unroll
            for (int mi = 0; mi < 4; ++mi)
                #pragma unroll
                for (int ni = 0; ni < 2; ++ni)
                    acc[mi + 4][ni] = __builtin_amdgcn_mfma_f32_16x16x32_bf16(
                        a1k1[mi], b0k1[ni], acc[mi + 4][ni], 0, 0, 0);
            #pragma unroll
            for (int mi = 0; mi < 4; ++mi)
                #pragma unroll
                for (int ni = 0; ni < 2; ++ni)
                    acc[mi + 4][ni + 2] = __builtin_amdgcn_mfma_f32_16x16x32_bf16(
                        a1k0[mi], b1k0[ni], acc[mi + 4][ni + 2], 0, 0, 0);
            #pragma unroll
            for (int mi = 0; mi < 4; ++mi)
                #pragma unroll
                for (int ni = 0; ni < 2; ++ni)
                    acc[mi + 4][ni + 2] = __builtin_amdgcn_mfma_f32_16x16x32_bf16(
                        a1k1[mi], b1k1[ni], acc[mi + 4][ni + 2], 0, 0, 0);
            __builtin_amdgcn_s_setprio(0);
        }
    }
#undef STG4

    // Epilogue: C/D layout col=lane&15, row=(lane>>4)*4+reg  [m89/m91 verified]
    OutT* __restrict__ Cb = C + (col0 >> cshift) * plane;
    const int ccol0 = (int)(col0 & (((long)1 << cshift) - 1));

    if (MODE == 1) {
        // P' = exp2(alpha*acc); row partial sums -> shfl over lr -> atomicAdd.
        #pragma unroll
        for (int mi = 0; mi < 8; ++mi)
            #pragma unroll
            for (int rg = 0; rg < 4; ++rg) {
                const long r = row0 + wm + mi * 16 + lq * 4 + rg;
                float part = 0.f;
                #pragma unroll
                for (int ni = 0; ni < 4; ++ni) {
                    const int cc = ccol0 + wn + ni * 16 + lr;
                    const float e = exp2f(alpha * acc[mi][ni][rg]);
                    part += e;
                    Cb[r * (long)ldc + cc] = (OutT)e;
                }
                part += __shfl_xor(part, 1);
                part += __shfl_xor(part, 2);
                part += __shfl_xor(part, 4);
                part += __shfl_xor(part, 8);
                if (lr == 0) atomicAdd(&lsum[r], part);
            }
    } else if (MODE == 2) {
        #pragma unroll
        for (int mi = 0; mi < 8; ++mi)
            #pragma unroll
            for (int rg = 0; rg < 4; ++rg) {
                const long r = row0 + wm + mi * 16 + lq * 4 + rg;
                const float inv = 1.0f / lsum[r];
                #pragma unroll
                for (int ni = 0; ni < 4; ++ni) {
                    const int cc = ccol0 + wn + ni * 16 + lr;
                    Cb[r * (long)ldc + cc] = (OutT)(acc[mi][ni][rg] * inv);
                }
            }
    } else {
        #pragma unroll
        for (int mi = 0; mi < 8; ++mi)
            #pragma unroll
            for (int ni = 0; ni < 4; ++ni)
                #pragma unroll
                for (int rg = 0; rg < 4; ++rg) {
                    const long r = row0 + wm + mi * 16 + lq * 4 + rg;
                    const int  cc = ccol0 + wn + ni * 16 + lr;
                    Cb[r * (long)ldc + cc] = (OutT)(alpha * acc[mi][ni][rg]);
                }
    }
}

// ---------------- bf16 transpose (strided in), v -> v^T ----------------
__global__ __launch_bounds__(256)
void transpose_bf16(const bf16_t* __restrict__ in, bf16_t* __restrict__ out,
                    int R, int ldin, int ldout)
{
    __shared__ bf16_t tile[32][33];
    const int tx = threadIdx.x & 31;
    const int ty = threadIdx.x >> 5;   // 0..7
    const int c0 = blockIdx.x * 32;
    const int r0 = blockIdx.y * 32;
    #pragma unroll
    for (int j = 0; j < 32; j += 8)
        tile[ty + j][tx] = in[(long)(r0 + ty + j) * ldin + c0 + tx];
    __syncthreads();
    #pragma unroll
    for (int j = 0; j < 32; j += 8)
        out[(long)(c0 + ty + j) * ldout + r0 + tx] = tile[tx][ty + j];
}

extern "C" void kernel_launch(void* const* d_in, const int* in_sizes, int n_in,
                              void* d_out, int out_size, void* d_ws, size_t ws_size,
                              hipStream_t stream)
{
    const float* x  = (const float*)d_in[0];
    const float* Wq = (const float*)d_in[1];
    const float* Wk = (const float*)d_in[2];
    const float* Wv = (const float*)d_in[3];
    float* out = (float*)d_out;

    char* ws = (char*)d_ws;
    const long XN = (long)SEQ * DMODEL;     // 8,388,608
    const long WN = (long)DMODEL * DMODEL;  // 1,048,576
    const long SN = (long)SEQ * SEQ;        // 67,108,864

    bf16_t* xb   = (bf16_t*)ws;                              // 16MB
    bf16_t* wcat = (bf16_t*)(ws + XN * 2);                   // 6MB [3072,1024]
    bf16_t* qb   = (bf16_t*)(ws + XN * 2 + WN * 6);          // 16MB compact
    bf16_t* kb   = qb + XN;                                  // 16MB compact
    bf16_t* vb   = qb + 2 * XN;                              // 16MB compact
    bf16_t* Sb   = (bf16_t*)(ws + XN * 2 + WN * 6 + XN * 6); // 128MB
    float*  pvp  = (float*)(ws + XN * 2 + WN * 6 + XN * 6 + SN * 2); // 32MB
    float*  lsum = (float*)(ws + XN * 2 + WN * 6 + XN * 6 + SN * 2 + XN * 4); // 32KB
    bf16_t* vtb  = xb;  // v^T overlays x_bf16 (x dead after QKV GEMM)

    const size_t base_need = (size_t)(XN * 2 + WN * 6 + XN * 6 + SN * 2);
    const bool use_split = ws_size >= base_need + XN * 4 + SEQ * 4;
    if (!use_split) lsum = (float*)(ws + base_need);  // reuse pvp slot

    convert_f32_bf16<<<(int)(XN / 4 / 256), 256, 0, stream>>>(x,  xb, XN);
    convert_f32_bf16<<<(int)(WN / 4 / 256), 256, 0, stream>>>(Wq, wcat,          WN);
    convert_f32_bf16<<<(int)(WN / 4 / 256), 256, 0, stream>>>(Wk, wcat + WN,     WN);
    convert_f32_bf16<<<(int)(WN / 4 / 256), 256, 0, stream>>>(Wv, wcat + 2 * WN, WN);
    zero_f32<<<SEQ / 256, 256, 0, stream>>>(lsum, SEQ);

    dim3 blk256(256);
    dim3 blk512(512);
    // qkv = x @ Wcat^T, de-interleaved into compact q|k|v (plane=XN, cshift=10)
    gemm_nt<bf16_t, 0, 1><<<(SEQ / 256) * (3 * DMODEL / 256), blk512, 0, stream>>>(
        xb, wcat, qb, qb, nullptr, SEQ, 3 * DMODEL, DMODEL,
        DMODEL, DMODEL, DMODEL, XN, 10, 1.0f);

    // v^T for the PV GEMM (writes over dead x_bf16)
    transpose_bf16<<<dim3(DMODEL / 32, SEQ / 32), blk256, 0, stream>>>(
        vb, vtb, SEQ, DMODEL, SEQ);

    // P' = exp2((q@k^T) * scale * log2e), bf16; row sums -> lsum (atomic)
    gemm_nt<bf16_t, 1, 1><<<(SEQ / 256) * (SEQ / 256), blk512, 0, stream>>>(
        qb, kb, Sb, Sb, lsum, SEQ, SEQ, DMODEL,
        DMODEL, DMODEL, SEQ, 0, 30, 0.03125f * LOG2E);

    // out = (P' @ v) / l  (PV epilogue applies 1/lsum[row]). Split-K=2 if ws.
    if (use_split) {
        gemm_nt<float, 2, 0><<<2 * (SEQ / 256) * (DMODEL / 256), blk512, 0, stream>>>(
            Sb, vtb, out, pvp, lsum, SEQ, DMODEL, SEQ / 2,
            SEQ, SEQ, DMODEL, 0, 30, 1.0f);
        add_f32<<<(int)(XN / 4 / 256), 256, 0, stream>>>(out, pvp, XN);
    } else {
        gemm_nt<float, 2, 0><<<(SEQ / 256) * (DMODEL / 256), blk512, 0, stream>>>(
            Sb, vtb, out, out, lsum, SEQ, DMODEL, SEQ,
            SEQ, SEQ, DMODEL, 0, 30, 1.0f);
    }
}